// Round 5
// baseline (1004.158 us; speedup 1.0000x reference)
//
#include <hip/hip_runtime.h>
#include <math.h>

typedef short short8 __attribute__((ext_vector_type(8)));
typedef float float4v __attribute__((ext_vector_type(4)));
#define AS1 __attribute__((address_space(1)))
#define AS3 __attribute__((address_space(3)))

__device__ __forceinline__ float b2f(ushort u) {
    unsigned v = ((unsigned)u) << 16; float f; __builtin_memcpy(&f, &v, 4); return f;
}
__device__ __forceinline__ ushort f2b(float f) {
    unsigned v; __builtin_memcpy(&v, &f, 4);
    unsigned r = (v + 0x7fffu + ((v >> 16) & 1u)) >> 16;
    return (ushort)r;
}

// ---------- fp32 -> bf16 convert with optional scale (and zero-pad rows) ----------
__global__ void cvt_pad(const float* __restrict__ src, ushort* __restrict__ dst,
                        int src_rows, int cols, int total4, float scl) {
    int i = blockIdx.x * 256 + threadIdx.x;
    if (i >= total4) return;
    size_t e = (size_t)i * 4;
    int r = (int)(e / (size_t)cols);
    ushort4 o;
    if (r < src_rows) {
        float4 v = *(const float4*)(src + e);
        o.x = f2b(v.x * scl); o.y = f2b(v.y * scl); o.z = f2b(v.z * scl); o.w = f2b(v.w * scl);
    } else {
        o.x = 0; o.y = 0; o.z = 0; o.w = 0;
    }
    *(ushort4*)(dst + e) = o;
}

// ---------- bf16 GEMM: C(MxN) = A(MxK) @ B(NxK)^T, strided ----------
// mode 0: bf16 C; mode 1: f32 C; mode 2: MLA kv scatter (Kf nope cols + Vt transposed V)
__global__ __launch_bounds__(256)
void gemm_bt(const ushort* __restrict__ A, const ushort* __restrict__ B,
             void* __restrict__ Cv, int K, int lda, int ldb, int ldc, int mode,
             ushort* __restrict__ Kf, ushort* __restrict__ Vtp) {
    __shared__ ushort sA[128 * 32];
    __shared__ ushort sB[128 * 32];
    const int tid = threadIdx.x;
    const int wave = tid >> 6, lane = tid & 63;
    const int bm = blockIdx.y * 128, bn = blockIdx.x * 128;
    const int wm = (wave >> 1) * 64, wn = (wave & 1) * 64;
    const int lq = lane & 15, quad = lane >> 4;
    float4v acc[4][4] = {};

    const int srow = wave * 32 + (lane >> 2);
    const int skc = (lane & 3) * 8;
    const ushort* Ag = A + (size_t)(bm + srow) * lda + skc;
    const ushort* Bg = B + (size_t)(bn + srow) * ldb + skc;
    ushort* sAw = sA + (wave * 32) * 32;
    ushort* sBw = sB + (wave * 32) * 32;

    for (int k0 = 0; k0 < K; k0 += 32) {
        __builtin_amdgcn_global_load_lds((const AS1 void*)(Ag + k0), (AS3 void*)sAw, 16, 0, 0);
        __builtin_amdgcn_global_load_lds((const AS1 void*)(Ag + (size_t)16 * lda + k0),
                                         (AS3 void*)(sAw + 16 * 32), 16, 0, 0);
        __builtin_amdgcn_global_load_lds((const AS1 void*)(Bg + k0), (AS3 void*)sBw, 16, 0, 0);
        __builtin_amdgcn_global_load_lds((const AS1 void*)(Bg + (size_t)16 * ldb + k0),
                                         (AS3 void*)(sBw + 16 * 32), 16, 0, 0);
        __syncthreads();
        short8 af[4], bfr[4];
#pragma unroll
        for (int i = 0; i < 4; ++i) {
            af[i]  = *(const short8*)(sA + (wm + i * 16 + lq) * 32 + quad * 8);
            bfr[i] = *(const short8*)(sB + (wn + i * 16 + lq) * 32 + quad * 8);
        }
#pragma unroll
        for (int i = 0; i < 4; ++i)
#pragma unroll
            for (int j = 0; j < 4; ++j)
                acc[i][j] = __builtin_amdgcn_mfma_f32_16x16x32_bf16(af[i], bfr[j], acc[i][j], 0, 0, 0);
        __syncthreads();
    }
#pragma unroll
    for (int i = 0; i < 4; ++i) {
        int row0 = bm + wm + i * 16 + quad * 4;
#pragma unroll
        for (int j = 0; j < 4; ++j) {
            int col = bn + wn + j * 16 + lq;
            if (mode == 0) {
                ushort* C = (ushort*)Cv;
#pragma unroll
                for (int r = 0; r < 4; ++r)
                    C[(size_t)(row0 + r) * ldc + col] = f2b(acc[i][j][r]);
            } else if (mode == 1) {
                float* C = (float*)Cv;
#pragma unroll
                for (int r = 0; r < 4; ++r)
                    C[(size_t)(row0 + r) * ldc + col] = acc[i][j][r];
            } else {
                // MLA kv scatter: col = h*256 + c; c<128 -> Kfull nope, else Vt transposed
                int h = col >> 8, c = col & 255;
                int bh = ((row0 >> 11) << 4) + h;
                if (c < 128) {
#pragma unroll
                    for (int r = 0; r < 4; ++r) {
                        int s = (row0 + r) & 2047;
                        Kf[((size_t)bh * 2048 + s) * 200 + c] = f2b(acc[i][j][r]);
                    }
                } else {
                    int d = c - 128;
                    int kt = (row0 & 2047) >> 6, kv = row0 & 63;
                    ushort4 o;
                    o.x = f2b(acc[i][j][0]); o.y = f2b(acc[i][j][1]);
                    o.z = f2b(acc[i][j][2]); o.w = f2b(acc[i][j][3]);
                    *(ushort4*)(Vtp + (((size_t)bh * 32 + kt) * 128 + d) * 72 + kv) = o;
                }
            }
        }
    }
}

// ---------- rmsnorm (in-place, one block per row, strided) ----------
__global__ void rmsnorm_inplace(ushort* __restrict__ d, const float* __restrict__ w,
                                int cols, int ld) {
    int row = blockIdx.x, tid = threadIdx.x;
    ushort* p = d + (size_t)row * ld;
    float ss = 0.f;
    for (int i = tid; i < cols; i += 256) { float v = b2f(p[i]); ss += v * v; }
#pragma unroll
    for (int off = 32; off >= 1; off >>= 1) ss += __shfl_xor(ss, off);
    __shared__ float red[4];
    if ((tid & 63) == 0) red[tid >> 6] = ss;
    __syncthreads();
    float tot = red[0] + red[1] + red[2] + red[3];
    float rs = rsqrtf(tot / (float)cols + 1e-6f);
    for (int i = tid; i < cols; i += 256) p[i] = f2b(b2f(p[i]) * rs * w[i]);
}

// ---------- kv norm (cols 0..512) + k_pe rope (cols 512..576), strided ----------
__global__ void kvnorm_rope(const ushort* __restrict__ kvraw, const float* __restrict__ w,
                            const float* __restrict__ freqs, ushort* __restrict__ kvc,
                            ushort* __restrict__ kpe, int ld) {
    int row = blockIdx.x, tid = threadIdx.x;
    int s = row & 2047;
    const ushort* p = kvraw + (size_t)row * ld;
    float v0 = b2f(p[tid]), v1 = b2f(p[tid + 256]);
    float ss = v0 * v0 + v1 * v1;
#pragma unroll
    for (int off = 32; off >= 1; off >>= 1) ss += __shfl_xor(ss, off);
    __shared__ float red[4];
    if ((tid & 63) == 0) red[tid >> 6] = ss;
    __syncthreads();
    float tot = red[0] + red[1] + red[2] + red[3];
    float rs = rsqrtf(tot / 512.f + 1e-6f);
    kvc[(size_t)row * 512 + tid] = f2b(v0 * rs * w[tid]);
    kvc[(size_t)row * 512 + tid + 256] = f2b(v1 * rs * w[tid + 256]);
    if (tid < 32) {
        float re = b2f(p[512 + 2 * tid]), im = b2f(p[512 + 2 * tid + 1]);
        float cs = freqs[(s * 32 + tid) * 2], sn = freqs[(s * 32 + tid) * 2 + 1];
        kpe[(size_t)row * 64 + 2 * tid] = f2b(re * cs - im * sn);
        kpe[(size_t)row * 64 + 2 * tid + 1] = f2b(re * sn + im * cs);
    }
}

// ---------- rope on q_pe (last 64 of each 192-dim head) ----------
__global__ void qrope(ushort* __restrict__ q, const float* __restrict__ freqs) {
    int idx = blockIdx.x * 256 + threadIdx.x;
    int i = idx & 31;
    int h = (idx >> 5) & 15;
    int srow = idx >> 9;
    int s = srow & 2047;
    ushort* p = q + ((size_t)srow * 16 + h) * 192 + 128 + 2 * i;
    float re = b2f(p[0]), im = b2f(p[1]);
    float cs = freqs[(s * 32 + i) * 2], sn = freqs[(s * 32 + i) * 2 + 1];
    p[0] = f2b(re * cs - im * sn);
    p[1] = f2b(re * sn + im * cs);
}

// ---------- fill roped k_pe into Kfull cols 128..191 (broadcast over h) ----------
__global__ void kpe_fill(const ushort* __restrict__ kpe, ushort* __restrict__ Kfull) {
    int tid = threadIdx.x;
    int row = blockIdx.x * 8 + (tid >> 5);   // row = bh*2048 + s
    int c = tid & 31;
    int bh = row >> 11, s = row & 2047, b = bh >> 4;
    ushort2 v;
    v.x = kpe[((size_t)b * 2048 + s) * 64 + 2 * c];
    v.y = kpe[((size_t)b * 2048 + s) * 64 + 2 * c + 1];
    *(ushort2*)(Kfull + (size_t)row * 200 + 128 + 2 * c) = v;
}

// ---------- causal flash attention: 8-wave blocks, QBLK=128, shared-K staging ----------
// R0-R2 flat at 130us with every pipe <25% busy and occupancy ~2.2 waves/SIMD ->
// latency-bound on the per-wave serial chain. R4 proved K must stay LDS-staged
// (L2-direct K = 186us) and V-hoisting from L2 is fine. Fix: 512-thread blocks,
// 8 waves x 16 q-rows = 128 q-rows share ONE staged K tile. LDS = sK 25.6K +
// sP 18.4K = 44KB -> 3 blocks/CU, up to 24 waves/CU (was 8.8). Tile-iters halve
// (stage covers 2x the q-rows). V direct from L2 (kc=0 hoisted under softmax).
__global__ __launch_bounds__(512, 5)
void mla_attn9(const ushort* __restrict__ q, const ushort* __restrict__ Kfull,
               const ushort* __restrict__ Vt, ushort* __restrict__ out) {
    __shared__ ushort sK[64 * 200];
    __shared__ ushort sP[8][16][72];
    const int tid = threadIdx.x, wave = tid >> 6, lane = tid & 63;
    const int lq = lane & 15, quad = lane >> 4;
    const int lin = blockIdx.x;
    const int e = lin & 7, idx = lin >> 3;
    const int st = 15 - (idx >> 2);          // 128-row q super-tile, big first
    const int bh = e + 8 * (idx & 3);        // XCD-pinned: bh%8 == lin%8
    const int b = bh >> 4, h = bh & 15;
    const ushort* Kb = Kfull + (size_t)bh * 2048 * 200;
    const ushort* Vb = Vt + (size_t)bh * 32 * 128 * 72;

    const int qrow = st * 128 + wave * 16 + lq;
    const ushort* qp = q + ((size_t)(b * 2048 + qrow) * 16 + h) * 192 + quad * 8;
    short8 qf[6];
#pragma unroll
    for (int c = 0; c < 6; ++c) qf[c] = *(const short8*)(qp + c * 32);

    float4v oacc[8] = {};
    float m_i[4] = {-INFINITY, -INFINITY, -INFINITY, -INFINITY};
    float l_i[4] = {0.f, 0.f, 0.f, 0.f};
    const int myrow0 = st * 128 + wave * 16 + quad * 4;
    const int ktmax = 2 * st + 1;

    for (int kt = 0; kt <= ktmax; ++kt) {
        // stage K tile (64x200 = 1600 16B-chunks) across all 512 threads
        const ushort* Ksrc = Kb + (size_t)kt * 64 * 200;
#pragma unroll
        for (int i = 0; i < 4; ++i) {
            int cb = i * 512 + wave * 64;    // wave-uniform chunk base
            if (cb < 1600)
                __builtin_amdgcn_global_load_lds((const AS1 void*)(Ksrc + (size_t)(cb + lane) * 8),
                                                 (AS3 void*)(sK + cb * 8), 16, 0, 0);
        }
        __syncthreads();
        const ushort* Vrow = Vb + (size_t)kt * 128 * 72 + (size_t)lq * 72 + quad * 8;
        // S = Q K^T (per wave: 16 x 64)
        float4v sc[4];
#pragma unroll
        for (int ct = 0; ct < 4; ++ct) {
            float4v a = {0.f, 0.f, 0.f, 0.f};
#pragma unroll
            for (int c = 0; c < 6; ++c) {
                short8 kf = *(const short8*)(sK + (ct * 16 + lq) * 200 + c * 32 + quad * 8);
                a = __builtin_amdgcn_mfma_f32_16x16x32_bf16(qf[c], kf, a, 0, 0, 0);
            }
            sc[ct] = a;
        }
        // hoist V loads for kc=0 from L2: independent, fly during softmax
        short8 vf0[8];
#pragma unroll
        for (int dt = 0; dt < 8; ++dt)
            vf0[dt] = *(const short8*)(Vrow + (size_t)dt * 16 * 72);
        // causal mask (branchless) + online softmax (base-2, scores pre-scaled)
        float mnew[4];
#pragma unroll
        for (int r = 0; r < 4; ++r) mnew[r] = m_i[r];
#pragma unroll
        for (int ct = 0; ct < 4; ++ct)
#pragma unroll
            for (int r = 0; r < 4; ++r) {
                float v = (kt * 64 + ct * 16 + lq) > (myrow0 + r) ? -INFINITY : sc[ct][r];
                sc[ct][r] = v;
                mnew[r] = fmaxf(mnew[r], v);
            }
#pragma unroll
        for (int off = 8; off >= 1; off >>= 1)
#pragma unroll
            for (int r = 0; r < 4; ++r) mnew[r] = fmaxf(mnew[r], __shfl_xor(mnew[r], off));
        // defer-max: rescale only if the max grew by > 8 (log2 domain)
        float g = mnew[0] - m_i[0];
#pragma unroll
        for (int r = 1; r < 4; ++r) g = fmaxf(g, mnew[r] - m_i[r]);
        if (__ballot(g > 8.0f) != 0ull) {
#pragma unroll
            for (int r = 0; r < 4; ++r) {
                float a = __builtin_amdgcn_exp2f(m_i[r] - mnew[r]);
                m_i[r] = mnew[r];
                l_i[r] *= a;
#pragma unroll
                for (int dt = 0; dt < 8; ++dt) oacc[dt][r] *= a;
            }
        }
        float psum[4] = {0.f, 0.f, 0.f, 0.f};
#pragma unroll
        for (int ct = 0; ct < 4; ++ct)
#pragma unroll
            for (int r = 0; r < 4; ++r) {
                float pv = __builtin_amdgcn_exp2f(sc[ct][r] - m_i[r]);
                psum[r] += pv;
                sP[wave][quad * 4 + r][ct * 16 + lq] = f2b(pv);
            }
#pragma unroll
        for (int off = 8; off >= 1; off >>= 1)
#pragma unroll
            for (int r = 0; r < 4; ++r) psum[r] += __shfl_xor(psum[r], off);
#pragma unroll
        for (int r = 0; r < 4; ++r) l_i[r] += psum[r];
        // O += P @ V (sP wave-private: same-wave DS order suffices; V from L2)
#pragma unroll
        for (int kc = 0; kc < 2; ++kc) {
            short8 pf = *(const short8*)(&sP[wave][lq][kc * 32 + quad * 8]);
#pragma unroll
            for (int dt = 0; dt < 8; ++dt) {
                short8 vf = kc == 0 ? vf0[dt]
                                    : *(const short8*)(Vrow + (size_t)dt * 16 * 72 + 32);
                oacc[dt] = __builtin_amdgcn_mfma_f32_16x16x32_bf16(pf, vf, oacc[dt], 0, 0, 0);
            }
        }
        __syncthreads();   // protect sK before next stage
    }
    float inv[4];
#pragma unroll
    for (int r = 0; r < 4; ++r) inv[r] = 1.f / l_i[r];
#pragma unroll
    for (int dt = 0; dt < 8; ++dt) {
#pragma unroll
        for (int r = 0; r < 4; ++r) {
            out[((size_t)(b * 2048 + myrow0 + r) * 16 + h) * 128 + dt * 16 + lq] =
                f2b(oacc[dt][r] * inv[r]);
        }
    }
}

// ---------- launch ----------
extern "C" void kernel_launch(void* const* d_in, const int* in_sizes, int n_in,
                              void* d_out, int out_size, void* d_ws, size_t ws_size,
                              hipStream_t stream) {
    const float* x     = (const float*)d_in[0];
    const float* freqs = (const float*)d_in[2];
    const float* wq_a  = (const float*)d_in[3];
    const float* qnw   = (const float*)d_in[4];
    const float* wq_b  = (const float*)d_in[5];
    const float* wkv_a = (const float*)d_in[6];
    const float* kvnw  = (const float*)d_in[7];
    const float* wkv_b = (const float*)d_in[8];
    const float* wo    = (const float*)d_in[9];

    char* ws = (char*)d_ws;
    size_t off = 0;
    auto alloc = [&](size_t n) { char* p = ws + off; off += (n + 255) & ~(size_t)255; return p; };
    ushort* xb    = (ushort*)alloc(4096ull * 2048 * 2);   // dead after fused a-gemm
    ushort* wqkva = (ushort*)alloc(2176ull * 2048 * 2);   // dead after fused a-gemm
    ushort* wqbb  = (ushort*)alloc(3072ull * 1536 * 2);   // dead after q_b gemm
    ushort* wkvbb = (ushort*)alloc(4096ull * 512 * 2);    // live until kv_b gemm
    ushort* wob   = (ushort*)alloc(2048ull * 2048 * 2);   // live until final gemm
    ushort* qakv  = (ushort*)alloc(4096ull * 2176 * 2);   // dead after q_b gemm
    ushort* kvc   = (ushort*)alloc(4096ull * 512 * 2);    // live until kv_b gemm
    ushort* kpe   = (ushort*)alloc(4096ull * 64 * 2);
    ushort* qfull = (ushort*)alloc(4096ull * 3072 * 2);
    ushort* kvbuf = (ushort*)alloc(4096ull * 4096 * 2);   // hosts Kfull (26.2 <= 33.6 MB)
    ushort* attno = (ushort*)alloc(4096ull * 2048 * 2);
    if (off > ws_size) return;
    // Kfull[32][2048][200] in kvbuf region (no aliasing).
    ushort* Kfull = kvbuf;
    // Vt[32][32][128][72] = 18.9 MB over xb+wqkva (25.7 MB), both dead before kv_b gemm.
    ushort* Vt = xb;

    auto cvt = [&](const float* s, ushort* dd, int sr, int cols, size_t dtot, float scl) {
        int t4 = (int)(dtot / 4);
        cvt_pad<<<(t4 + 255) / 256, 256, 0, stream>>>(s, dd, sr, cols, t4, scl);
    };
    // bake softmax_scale * log2(e) into wq_b so attn scores land pre-scaled in log2 domain
    const float qk_scale = 1.44269504f / sqrtf(192.0f);
    cvt(x, xb, 4096, 2048, 4096ull * 2048, 1.f);
    cvt(wq_a, wqkva, 1536, 2048, 1536ull * 2048, 1.f);
    cvt(wkv_a, wqkva + 1536ull * 2048, 576, 2048, 640ull * 2048, 1.f);
    cvt(wq_b, wqbb, 3072, 1536, 3072ull * 1536, qk_scale);
    cvt(wkv_b, wkvbb, 4096, 512, 4096ull * 512, 1.f);
    cvt(wo, wob, 2048, 2048, 2048ull * 2048, 1.f);

    // fused q_a + kv_a projection: [4096 x 2048] @ [2176 x 2048]^T
    gemm_bt<<<dim3(17, 32), 256, 0, stream>>>(xb, wqkva, qakv, 2048, 2048, 2048, 2176, 0, nullptr, nullptr);
    rmsnorm_inplace<<<4096, 256, 0, stream>>>(qakv, qnw, 1536, 2176);
    kvnorm_rope<<<4096, 256, 0, stream>>>(qakv + 1536, kvnw, freqs, kvc, kpe, 2176);
    gemm_bt<<<dim3(24, 32), 256, 0, stream>>>(qakv, wqbb, qfull, 1536, 2176, 1536, 3072, 0, nullptr, nullptr);
    qrope<<<8192, 256, 0, stream>>>(qfull, freqs);
    kpe_fill<<<8192, 256, 0, stream>>>(kpe, Kfull);
    // kv_b gemm with fused scatter epilogue: writes Kfull nope cols + transposed Vt
    // (xb/wqkva dead -> Vt region safe; qakv dead)
    gemm_bt<<<dim3(32, 32), 256, 0, stream>>>(kvc, wkvbb, nullptr, 512, 512, 512, 0, 2, Kfull, Vt);
    mla_attn9<<<dim3(512), 512, 0, stream>>>(qfull, Kfull, Vt, attno);
    gemm_bt<<<dim3(16, 32), 256, 0, stream>>>(attno, wob, (float*)d_out, 2048, 2048, 2048, 2048, 1, nullptr, nullptr);
}

// Round 6
// 499.866 us; speedup vs baseline: 2.0089x; 2.0089x over previous
//
#include <hip/hip_runtime.h>
#include <math.h>

typedef short short8 __attribute__((ext_vector_type(8)));
typedef float float4v __attribute__((ext_vector_type(4)));
#define AS1 __attribute__((address_space(1)))
#define AS3 __attribute__((address_space(3)))

__device__ __forceinline__ float b2f(ushort u) {
    unsigned v = ((unsigned)u) << 16; float f; __builtin_memcpy(&f, &v, 4); return f;
}
__device__ __forceinline__ ushort f2b(float f) {
    unsigned v; __builtin_memcpy(&v, &f, 4);
    unsigned r = (v + 0x7fffu + ((v >> 16) & 1u)) >> 16;
    return (ushort)r;
}

// ---------- fp32 -> bf16 convert with optional scale (and zero-pad rows) ----------
__global__ void cvt_pad(const float* __restrict__ src, ushort* __restrict__ dst,
                        int src_rows, int cols, int total4, float scl) {
    int i = blockIdx.x * 256 + threadIdx.x;
    if (i >= total4) return;
    size_t e = (size_t)i * 4;
    int r = (int)(e / (size_t)cols);
    ushort4 o;
    if (r < src_rows) {
        float4 v = *(const float4*)(src + e);
        o.x = f2b(v.x * scl); o.y = f2b(v.y * scl); o.z = f2b(v.z * scl); o.w = f2b(v.w * scl);
    } else {
        o.x = 0; o.y = 0; o.z = 0; o.w = 0;
    }
    *(ushort4*)(dst + e) = o;
}

// ---------- bf16 GEMM: C(MxN) = A(MxK) @ B(NxK)^T, strided ----------
// mode 0: bf16 C; mode 1: f32 C; mode 2: MLA kv scatter (Kf nope cols + Vt transposed V)
__global__ __launch_bounds__(256)
void gemm_bt(const ushort* __restrict__ A, const ushort* __restrict__ B,
             void* __restrict__ Cv, int K, int lda, int ldb, int ldc, int mode,
             ushort* __restrict__ Kf, ushort* __restrict__ Vtp) {
    __shared__ ushort sA[128 * 32];
    __shared__ ushort sB[128 * 32];
    const int tid = threadIdx.x;
    const int wave = tid >> 6, lane = tid & 63;
    const int bm = blockIdx.y * 128, bn = blockIdx.x * 128;
    const int wm = (wave >> 1) * 64, wn = (wave & 1) * 64;
    const int lq = lane & 15, quad = lane >> 4;
    float4v acc[4][4] = {};

    const int srow = wave * 32 + (lane >> 2);
    const int skc = (lane & 3) * 8;
    const ushort* Ag = A + (size_t)(bm + srow) * lda + skc;
    const ushort* Bg = B + (size_t)(bn + srow) * ldb + skc;
    ushort* sAw = sA + (wave * 32) * 32;
    ushort* sBw = sB + (wave * 32) * 32;

    for (int k0 = 0; k0 < K; k0 += 32) {
        __builtin_amdgcn_global_load_lds((const AS1 void*)(Ag + k0), (AS3 void*)sAw, 16, 0, 0);
        __builtin_amdgcn_global_load_lds((const AS1 void*)(Ag + (size_t)16 * lda + k0),
                                         (AS3 void*)(sAw + 16 * 32), 16, 0, 0);
        __builtin_amdgcn_global_load_lds((const AS1 void*)(Bg + k0), (AS3 void*)sBw, 16, 0, 0);
        __builtin_amdgcn_global_load_lds((const AS1 void*)(Bg + (size_t)16 * ldb + k0),
                                         (AS3 void*)(sBw + 16 * 32), 16, 0, 0);
        __syncthreads();
        short8 af[4], bfr[4];
#pragma unroll
        for (int i = 0; i < 4; ++i) {
            af[i]  = *(const short8*)(sA + (wm + i * 16 + lq) * 32 + quad * 8);
            bfr[i] = *(const short8*)(sB + (wn + i * 16 + lq) * 32 + quad * 8);
        }
#pragma unroll
        for (int i = 0; i < 4; ++i)
#pragma unroll
            for (int j = 0; j < 4; ++j)
                acc[i][j] = __builtin_amdgcn_mfma_f32_16x16x32_bf16(af[i], bfr[j], acc[i][j], 0, 0, 0);
        __syncthreads();
    }
#pragma unroll
    for (int i = 0; i < 4; ++i) {
        int row0 = bm + wm + i * 16 + quad * 4;
#pragma unroll
        for (int j = 0; j < 4; ++j) {
            int col = bn + wn + j * 16 + lq;
            if (mode == 0) {
                ushort* C = (ushort*)Cv;
#pragma unroll
                for (int r = 0; r < 4; ++r)
                    C[(size_t)(row0 + r) * ldc + col] = f2b(acc[i][j][r]);
            } else if (mode == 1) {
                float* C = (float*)Cv;
#pragma unroll
                for (int r = 0; r < 4; ++r)
                    C[(size_t)(row0 + r) * ldc + col] = acc[i][j][r];
            } else {
                // MLA kv scatter: col = h*256 + c; c<128 -> Kfull nope, else Vt transposed
                int h = col >> 8, c = col & 255;
                int bh = ((row0 >> 11) << 4) + h;
                if (c < 128) {
#pragma unroll
                    for (int r = 0; r < 4; ++r) {
                        int s = (row0 + r) & 2047;
                        Kf[((size_t)bh * 2048 + s) * 200 + c] = f2b(acc[i][j][r]);
                    }
                } else {
                    int d = c - 128;
                    int kt = (row0 & 2047) >> 6, kv = row0 & 63;
                    ushort4 o;
                    o.x = f2b(acc[i][j][0]); o.y = f2b(acc[i][j][1]);
                    o.z = f2b(acc[i][j][2]); o.w = f2b(acc[i][j][3]);
                    *(ushort4*)(Vtp + (((size_t)bh * 32 + kt) * 128 + d) * 72 + kv) = o;
                }
            }
        }
    }
}

// ---------- rmsnorm (in-place, one block per row, strided) ----------
__global__ void rmsnorm_inplace(ushort* __restrict__ d, const float* __restrict__ w,
                                int cols, int ld) {
    int row = blockIdx.x, tid = threadIdx.x;
    ushort* p = d + (size_t)row * ld;
    float ss = 0.f;
    for (int i = tid; i < cols; i += 256) { float v = b2f(p[i]); ss += v * v; }
#pragma unroll
    for (int off = 32; off >= 1; off >>= 1) ss += __shfl_xor(ss, off);
    __shared__ float red[4];
    if ((tid & 63) == 0) red[tid >> 6] = ss;
    __syncthreads();
    float tot = red[0] + red[1] + red[2] + red[3];
    float rs = rsqrtf(tot / (float)cols + 1e-6f);
    for (int i = tid; i < cols; i += 256) p[i] = f2b(b2f(p[i]) * rs * w[i]);
}

// ---------- kv norm (cols 0..512) + k_pe rope (cols 512..576), strided ----------
__global__ void kvnorm_rope(const ushort* __restrict__ kvraw, const float* __restrict__ w,
                            const float* __restrict__ freqs, ushort* __restrict__ kvc,
                            ushort* __restrict__ kpe, int ld) {
    int row = blockIdx.x, tid = threadIdx.x;
    int s = row & 2047;
    const ushort* p = kvraw + (size_t)row * ld;
    float v0 = b2f(p[tid]), v1 = b2f(p[tid + 256]);
    float ss = v0 * v0 + v1 * v1;
#pragma unroll
    for (int off = 32; off >= 1; off >>= 1) ss += __shfl_xor(ss, off);
    __shared__ float red[4];
    if ((tid & 63) == 0) red[tid >> 6] = ss;
    __syncthreads();
    float tot = red[0] + red[1] + red[2] + red[3];
    float rs = rsqrtf(tot / 512.f + 1e-6f);
    kvc[(size_t)row * 512 + tid] = f2b(v0 * rs * w[tid]);
    kvc[(size_t)row * 512 + tid + 256] = f2b(v1 * rs * w[tid + 256]);
    if (tid < 32) {
        float re = b2f(p[512 + 2 * tid]), im = b2f(p[512 + 2 * tid + 1]);
        float cs = freqs[(s * 32 + tid) * 2], sn = freqs[(s * 32 + tid) * 2 + 1];
        kpe[(size_t)row * 64 + 2 * tid] = f2b(re * cs - im * sn);
        kpe[(size_t)row * 64 + 2 * tid + 1] = f2b(re * sn + im * cs);
    }
}

// ---------- rope on q_pe (last 64 of each 192-dim head) ----------
__global__ void qrope(ushort* __restrict__ q, const float* __restrict__ freqs) {
    int idx = blockIdx.x * 256 + threadIdx.x;
    int i = idx & 31;
    int h = (idx >> 5) & 15;
    int srow = idx >> 9;
    int s = srow & 2047;
    ushort* p = q + ((size_t)srow * 16 + h) * 192 + 128 + 2 * i;
    float re = b2f(p[0]), im = b2f(p[1]);
    float cs = freqs[(s * 32 + i) * 2], sn = freqs[(s * 32 + i) * 2 + 1];
    p[0] = f2b(re * cs - im * sn);
    p[1] = f2b(re * sn + im * cs);
}

// ---------- fill roped k_pe into Kfull cols 128..191 (broadcast over h) ----------
__global__ void kpe_fill(const ushort* __restrict__ kpe, ushort* __restrict__ Kfull) {
    int tid = threadIdx.x;
    int row = blockIdx.x * 8 + (tid >> 5);   // row = bh*2048 + s
    int c = tid & 31;
    int bh = row >> 11, s = row & 2047, b = bh >> 4;
    ushort2 v;
    v.x = kpe[((size_t)b * 2048 + s) * 64 + 2 * c];
    v.y = kpe[((size_t)b * 2048 + s) * 64 + 2 * c + 1];
    *(ushort2*)(Kfull + (size_t)row * 200 + 128 + 2 * c) = v;
}

// ---------- causal flash attention: 8-wave blocks, QBLK=128, shared-K staging ----------
// R5 lesson: __launch_bounds__(512,5) forced VGPR=48 -> total spill catastrophe
// (WRITE_SIZE 1.23GB of scratch). Structure itself passed correctness. Fix: bounds
// (512,2) -> compiler lands ~100-110 VGPR (as the same body did at 256 threads),
// 4 waves/SIMD = 16 waves/CU = 2 blocks/CU: 2x the resident waves of the 130us
// baseline, with HALF the stage+barrier iterations (one K-stage per 128 q-rows).
// K stays LDS-staged (R4: L2-direct K = 186us); V direct from L2 (R4: benign).
__global__ __launch_bounds__(512, 2)
void mla_attn9(const ushort* __restrict__ q, const ushort* __restrict__ Kfull,
               const ushort* __restrict__ Vt, ushort* __restrict__ out) {
    __shared__ ushort sK[64 * 200];
    __shared__ ushort sP[8][16][72];
    const int tid = threadIdx.x, wave = tid >> 6, lane = tid & 63;
    const int lq = lane & 15, quad = lane >> 4;
    const int lin = blockIdx.x;
    const int e = lin & 7, idx = lin >> 3;
    const int st = 15 - (idx >> 2);          // 128-row q super-tile, big first
    const int bh = e + 8 * (idx & 3);        // XCD-pinned: bh%8 == lin%8
    const int b = bh >> 4, h = bh & 15;
    const ushort* Kb = Kfull + (size_t)bh * 2048 * 200;
    const ushort* Vb = Vt + (size_t)bh * 32 * 128 * 72;

    const int qrow = st * 128 + wave * 16 + lq;
    const ushort* qp = q + ((size_t)(b * 2048 + qrow) * 16 + h) * 192 + quad * 8;
    short8 qf[6];
#pragma unroll
    for (int c = 0; c < 6; ++c) qf[c] = *(const short8*)(qp + c * 32);

    float4v oacc[8] = {};
    float m_i[4] = {-INFINITY, -INFINITY, -INFINITY, -INFINITY};
    float l_i[4] = {0.f, 0.f, 0.f, 0.f};
    const int myrow0 = st * 128 + wave * 16 + quad * 4;
    const int ktmax = 2 * st + 1;

    for (int kt = 0; kt <= ktmax; ++kt) {
        // stage K tile (64x200 = 1600 16B-chunks) across all 512 threads
        const ushort* Ksrc = Kb + (size_t)kt * 64 * 200;
#pragma unroll
        for (int i = 0; i < 4; ++i) {
            int cb = i * 512 + wave * 64;    // wave-uniform chunk base
            if (cb < 1600)
                __builtin_amdgcn_global_load_lds((const AS1 void*)(Ksrc + (size_t)(cb + lane) * 8),
                                                 (AS3 void*)(sK + cb * 8), 16, 0, 0);
        }
        __syncthreads();
        const ushort* Vrow = Vb + (size_t)kt * 128 * 72 + (size_t)lq * 72 + quad * 8;
        // S = Q K^T (per wave: 16 x 64)
        float4v sc[4];
#pragma unroll
        for (int ct = 0; ct < 4; ++ct) {
            float4v a = {0.f, 0.f, 0.f, 0.f};
#pragma unroll
            for (int c = 0; c < 6; ++c) {
                short8 kf = *(const short8*)(sK + (ct * 16 + lq) * 200 + c * 32 + quad * 8);
                a = __builtin_amdgcn_mfma_f32_16x16x32_bf16(qf[c], kf, a, 0, 0, 0);
            }
            sc[ct] = a;
        }
        // hoist V loads for kc=0 from L2: independent, fly during softmax
        short8 vf0[8];
#pragma unroll
        for (int dt = 0; dt < 8; ++dt)
            vf0[dt] = *(const short8*)(Vrow + (size_t)dt * 16 * 72);
        // causal mask (branchless) + online softmax (base-2, scores pre-scaled)
        float mnew[4];
#pragma unroll
        for (int r = 0; r < 4; ++r) mnew[r] = m_i[r];
#pragma unroll
        for (int ct = 0; ct < 4; ++ct)
#pragma unroll
            for (int r = 0; r < 4; ++r) {
                float v = (kt * 64 + ct * 16 + lq) > (myrow0 + r) ? -INFINITY : sc[ct][r];
                sc[ct][r] = v;
                mnew[r] = fmaxf(mnew[r], v);
            }
#pragma unroll
        for (int off = 8; off >= 1; off >>= 1)
#pragma unroll
            for (int r = 0; r < 4; ++r) mnew[r] = fmaxf(mnew[r], __shfl_xor(mnew[r], off));
        // defer-max: rescale only if the max grew by > 8 (log2 domain)
        float g = mnew[0] - m_i[0];
#pragma unroll
        for (int r = 1; r < 4; ++r) g = fmaxf(g, mnew[r] - m_i[r]);
        if (__ballot(g > 8.0f) != 0ull) {
#pragma unroll
            for (int r = 0; r < 4; ++r) {
                float a = __builtin_amdgcn_exp2f(m_i[r] - mnew[r]);
                m_i[r] = mnew[r];
                l_i[r] *= a;
#pragma unroll
                for (int dt = 0; dt < 8; ++dt) oacc[dt][r] *= a;
            }
        }
        float psum[4] = {0.f, 0.f, 0.f, 0.f};
#pragma unroll
        for (int ct = 0; ct < 4; ++ct)
#pragma unroll
            for (int r = 0; r < 4; ++r) {
                float pv = __builtin_amdgcn_exp2f(sc[ct][r] - m_i[r]);
                psum[r] += pv;
                sP[wave][quad * 4 + r][ct * 16 + lq] = f2b(pv);
            }
#pragma unroll
        for (int off = 8; off >= 1; off >>= 1)
#pragma unroll
            for (int r = 0; r < 4; ++r) psum[r] += __shfl_xor(psum[r], off);
#pragma unroll
        for (int r = 0; r < 4; ++r) l_i[r] += psum[r];
        // O += P @ V (sP wave-private: same-wave DS order suffices; V from L2)
#pragma unroll
        for (int kc = 0; kc < 2; ++kc) {
            short8 pf = *(const short8*)(&sP[wave][lq][kc * 32 + quad * 8]);
#pragma unroll
            for (int dt = 0; dt < 8; ++dt) {
                short8 vf = kc == 0 ? vf0[dt]
                                    : *(const short8*)(Vrow + (size_t)dt * 16 * 72 + 32);
                oacc[dt] = __builtin_amdgcn_mfma_f32_16x16x32_bf16(pf, vf, oacc[dt], 0, 0, 0);
            }
        }
        __syncthreads();   // protect sK before next stage
    }
    float inv[4];
#pragma unroll
    for (int r = 0; r < 4; ++r) inv[r] = 1.f / l_i[r];
#pragma unroll
    for (int dt = 0; dt < 8; ++dt) {
#pragma unroll
        for (int r = 0; r < 4; ++r) {
            out[((size_t)(b * 2048 + myrow0 + r) * 16 + h) * 128 + dt * 16 + lq] =
                f2b(oacc[dt][r] * inv[r]);
        }
    }
}

// ---------- launch ----------
extern "C" void kernel_launch(void* const* d_in, const int* in_sizes, int n_in,
                              void* d_out, int out_size, void* d_ws, size_t ws_size,
                              hipStream_t stream) {
    const float* x     = (const float*)d_in[0];
    const float* freqs = (const float*)d_in[2];
    const float* wq_a  = (const float*)d_in[3];
    const float* qnw   = (const float*)d_in[4];
    const float* wq_b  = (const float*)d_in[5];
    const float* wkv_a = (const float*)d_in[6];
    const float* kvnw  = (const float*)d_in[7];
    const float* wkv_b = (const float*)d_in[8];
    const float* wo    = (const float*)d_in[9];

    char* ws = (char*)d_ws;
    size_t off = 0;
    auto alloc = [&](size_t n) { char* p = ws + off; off += (n + 255) & ~(size_t)255; return p; };
    ushort* xb    = (ushort*)alloc(4096ull * 2048 * 2);   // dead after fused a-gemm
    ushort* wqkva = (ushort*)alloc(2176ull * 2048 * 2);   // dead after fused a-gemm
    ushort* wqbb  = (ushort*)alloc(3072ull * 1536 * 2);   // dead after q_b gemm
    ushort* wkvbb = (ushort*)alloc(4096ull * 512 * 2);    // live until kv_b gemm
    ushort* wob   = (ushort*)alloc(2048ull * 2048 * 2);   // live until final gemm
    ushort* qakv  = (ushort*)alloc(4096ull * 2176 * 2);   // dead after q_b gemm
    ushort* kvc   = (ushort*)alloc(4096ull * 512 * 2);    // live until kv_b gemm
    ushort* kpe   = (ushort*)alloc(4096ull * 64 * 2);
    ushort* qfull = (ushort*)alloc(4096ull * 3072 * 2);
    ushort* kvbuf = (ushort*)alloc(4096ull * 4096 * 2);   // hosts Kfull (26.2 <= 33.6 MB)
    ushort* attno = (ushort*)alloc(4096ull * 2048 * 2);
    if (off > ws_size) return;
    // Kfull[32][2048][200] in kvbuf region (no aliasing).
    ushort* Kfull = kvbuf;
    // Vt[32][32][128][72] = 18.9 MB over xb+wqkva (25.7 MB), both dead before kv_b gemm.
    ushort* Vt = xb;

    auto cvt = [&](const float* s, ushort* dd, int sr, int cols, size_t dtot, float scl) {
        int t4 = (int)(dtot / 4);
        cvt_pad<<<(t4 + 255) / 256, 256, 0, stream>>>(s, dd, sr, cols, t4, scl);
    };
    // bake softmax_scale * log2(e) into wq_b so attn scores land pre-scaled in log2 domain
    const float qk_scale = 1.44269504f / sqrtf(192.0f);
    cvt(x, xb, 4096, 2048, 4096ull * 2048, 1.f);
    cvt(wq_a, wqkva, 1536, 2048, 1536ull * 2048, 1.f);
    cvt(wkv_a, wqkva + 1536ull * 2048, 576, 2048, 640ull * 2048, 1.f);
    cvt(wq_b, wqbb, 3072, 1536, 3072ull * 1536, qk_scale);
    cvt(wkv_b, wkvbb, 4096, 512, 4096ull * 512, 1.f);
    cvt(wo, wob, 2048, 2048, 2048ull * 2048, 1.f);

    // fused q_a + kv_a projection: [4096 x 2048] @ [2176 x 2048]^T
    gemm_bt<<<dim3(17, 32), 256, 0, stream>>>(xb, wqkva, qakv, 2048, 2048, 2048, 2176, 0, nullptr, nullptr);
    rmsnorm_inplace<<<4096, 256, 0, stream>>>(qakv, qnw, 1536, 2176);
    kvnorm_rope<<<4096, 256, 0, stream>>>(qakv + 1536, kvnw, freqs, kvc, kpe, 2176);
    gemm_bt<<<dim3(24, 32), 256, 0, stream>>>(qakv, wqbb, qfull, 1536, 2176, 1536, 3072, 0, nullptr, nullptr);
    qrope<<<8192, 256, 0, stream>>>(qfull, freqs);
    kpe_fill<<<8192, 256, 0, stream>>>(kpe, Kfull);
    // kv_b gemm with fused scatter epilogue: writes Kfull nope cols + transposed Vt
    // (xb/wqkva dead -> Vt region safe; qakv dead)
    gemm_bt<<<dim3(32, 32), 256, 0, stream>>>(kvc, wkvbb, nullptr, 512, 512, 512, 0, 2, Kfull, Vt);
    mla_attn9<<<dim3(512), 512, 0, stream>>>(qfull, Kfull, Vt, attno);
    gemm_bt<<<dim3(16, 32), 256, 0, stream>>>(attno, wob, (float*)d_out, 2048, 2048, 2048, 2048, 1, nullptr, nullptr);
}